// Round 1
// baseline (1614.857 us; speedup 1.0000x reference)
//
#include <hip/hip_runtime.h>

#define HH 8
#define DH 16
#define FOUT 128
#define DIN 64
#define NSLOPE 0.2f

__device__ __forceinline__ float fast_rcp(float x) { return __builtin_amdgcn_rcpf(x); }

__device__ __forceinline__ float fast_tanh(float x) {
    float ax = fabsf(x);
    float e = __expf(-2.f * ax);
    float r = (1.f - e) * fast_rcp(1.f + e);
    return x >= 0.f ? r : -r;
}

// GEMM: h[n] = x[n] @ W + b   (Din=64 -> F=128), plus per-node attention logits
// a_k[n,h] = sum_d h[n, h*16+d] * att_k[h*16+d]   for up to 3 att vectors.
__global__ __launch_bounds__(256) void k_lin(
    const float* __restrict__ x, const float* __restrict__ W, const float* __restrict__ b,
    const float* __restrict__ att0, const float* __restrict__ att1, const float* __restrict__ att2,
    float* __restrict__ hout,
    float* __restrict__ a0, float* __restrict__ a1, float* __restrict__ a2,
    int N, int natt)
{
    __shared__ float Wl[DIN * FOUT];   // 32 KB, [fi][fo] row-major (same as global)
    __shared__ float bl[FOUT];
    __shared__ float attl[3][FOUT];
    const int tid = threadIdx.x;
    for (int i = tid; i < DIN * FOUT / 4; i += 256)
        ((float4*)Wl)[i] = ((const float4*)W)[i];
    if (tid < FOUT) {
        bl[tid] = b[tid];
        attl[0][tid] = att0[tid];
        attl[1][tid] = natt > 1 ? att1[tid] : 0.f;
        attl[2][tid] = natt > 2 ? att2[tid] : 0.f;
    }
    __syncthreads();
    const int n = blockIdx.x * 256 + tid;
    if (n >= N) return;

    float xr[DIN];
    const float4* xp = (const float4*)(x + (size_t)n * DIN);
    #pragma unroll
    for (int i = 0; i < DIN / 4; i++) {
        float4 v = xp[i];
        xr[4*i] = v.x; xr[4*i+1] = v.y; xr[4*i+2] = v.z; xr[4*i+3] = v.w;
    }
    float4* hp = (float4*)(hout + (size_t)n * FOUT);
    for (int h = 0; h < HH; h++) {
        float aa0 = 0.f, aa1 = 0.f, aa2 = 0.f;
        #pragma unroll
        for (int g = 0; g < 4; g++) {
            const int fo = h * 16 + g * 4;
            float4 acc = *(const float4*)&bl[fo];
            #pragma unroll
            for (int fi = 0; fi < DIN; fi++) {
                float4 wv = *(const float4*)&Wl[fi * FOUT + fo];   // uniform addr -> LDS broadcast
                float xv = xr[fi];
                acc.x = fmaf(xv, wv.x, acc.x);
                acc.y = fmaf(xv, wv.y, acc.y);
                acc.z = fmaf(xv, wv.z, acc.z);
                acc.w = fmaf(xv, wv.w, acc.w);
            }
            hp[h * 4 + g] = acc;
            float4 t0 = *(const float4*)&attl[0][fo];
            aa0 += acc.x*t0.x + acc.y*t0.y + acc.z*t0.z + acc.w*t0.w;
            if (natt > 1) {
                float4 t1 = *(const float4*)&attl[1][fo];
                aa1 += acc.x*t1.x + acc.y*t1.y + acc.z*t1.z + acc.w*t1.w;
                float4 t2 = *(const float4*)&attl[2][fo];
                aa2 += acc.x*t2.x + acc.y*t2.y + acc.z*t2.z + acc.w*t2.w;
            }
        }
        a0[(size_t)n * HH + h] = aa0;
        if (natt > 1) {
            a1[(size_t)n * HH + h] = aa1;
            a2[(size_t)n * HH + h] = aa2;
        }
    }
}

// One 64-lane wave per edge. w_e,h = exp(leakyrelu(a_src[src,h]+a_dst[dst,h]))
// num[dst, f] += w * x_src[src, f]   (lane covers float2 -> 512B coalesced gather)
// den[dst, h] += w                   (one lane per head)
// Softmax normalization is deferred: out = num/(den+1e-16) later. Skipping the
// segment-max is exact for the e/sum(e) ratio; logits are small so exp is safe.
__global__ __launch_bounds__(256) void k_msg(
    const int* __restrict__ edges, int E,
    const float* __restrict__ xsrc,
    const float* __restrict__ asrc, const float* __restrict__ adst,
    float* __restrict__ onum, float* __restrict__ sden)
{
    int t = blockIdx.x * 256 + threadIdx.x;
    int e = t >> 6;
    if (e >= E) return;
    int lane = t & 63;
    int src = edges[e];
    int dst = edges[E + e];
    int h = lane >> 3;
    float a = asrc[(size_t)src * HH + h] + adst[(size_t)dst * HH + h];
    a = a > 0.f ? a : NSLOPE * a;
    float wv = __expf(a);
    float2 xv = *(const float2*)&xsrc[(size_t)src * FOUT + lane * 2];
    float* op = onum + (size_t)dst * FOUT + lane * 2;
    atomicAdd(op, wv * xv.x);
    atomicAdd(op + 1, wv * xv.y);
    if ((lane & 7) == 0) atomicAdd(sden + (size_t)dst * HH + h, wv);
}

// Normalize+relu o_m in place, then per-node partial of
// score[m] = sum_n sum_f q[f] * tanh((o_m[n] @ k_w)[f] + k_b[f]); block-reduce, atomic.
__global__ __launch_bounds__(256) void k_sem(
    float* __restrict__ o1, float* __restrict__ o2,
    const float* __restrict__ s1, const float* __restrict__ s2,
    const float* __restrict__ kw, const float* __restrict__ kb, const float* __restrict__ q,
    float* __restrict__ score, int N)
{
    __shared__ float kwl[FOUT * FOUT];  // 64 KB
    __shared__ float kbl[FOUT];
    __shared__ float ql[FOUT];
    __shared__ float red[256];
    const int tid = threadIdx.x;
    for (int i = tid; i < FOUT * FOUT / 4; i += 256)
        ((float4*)kwl)[i] = ((const float4*)kw)[i];
    if (tid < FOUT) { kbl[tid] = kb[tid]; ql[tid] = q[tid]; }
    __syncthreads();
    const int m = blockIdx.y;
    float* o = m ? o2 : o1;
    const float* s = m ? s2 : s1;
    const int n = blockIdx.x * 256 + tid;
    float part = 0.f;
    if (n < N) {
        float row[FOUT];
        float4* op = (float4*)(o + (size_t)n * FOUT);
        const float* sp = s + (size_t)n * HH;
        #pragma unroll
        for (int i = 0; i < FOUT / 4; i++) {     // fully unrolled -> row[] stays in VGPRs
            float4 v = op[i];
            float inv = fast_rcp(sp[i >> 2] + 1e-16f);
            v.x = fmaxf(v.x * inv, 0.f);
            v.y = fmaxf(v.y * inv, 0.f);
            v.z = fmaxf(v.z * inv, 0.f);
            v.w = fmaxf(v.w * inv, 0.f);
            op[i] = v;                            // write normalized o back for k_final
            row[4*i] = v.x; row[4*i+1] = v.y; row[4*i+2] = v.z; row[4*i+3] = v.w;
        }
        for (int fo4 = 0; fo4 < FOUT / 4; fo4++) {
            float4 acc = *(const float4*)&kbl[fo4 * 4];
            #pragma unroll
            for (int fi = 0; fi < FOUT; fi++) {   // fully unrolled -> const index into row[]
                float4 wv = *(const float4*)&kwl[fi * FOUT + fo4 * 4];
                float xv = row[fi];
                acc.x = fmaf(xv, wv.x, acc.x);
                acc.y = fmaf(xv, wv.y, acc.y);
                acc.z = fmaf(xv, wv.z, acc.z);
                acc.w = fmaf(xv, wv.w, acc.w);
            }
            const float4 qv = *(const float4*)&ql[fo4 * 4];
            part += fast_tanh(acc.x) * qv.x + fast_tanh(acc.y) * qv.y
                  + fast_tanh(acc.z) * qv.z + fast_tanh(acc.w) * qv.w;
        }
    }
    red[tid] = part;
    __syncthreads();
    for (int w = 128; w > 0; w >>= 1) {
        if (tid < w) red[tid] += red[tid + w];
        __syncthreads();
    }
    if (tid == 0) atomicAdd(score + m, red[0]);
}

__global__ void k_attn(const float* __restrict__ score, float* __restrict__ attn, float invN) {
    if (threadIdx.x == 0) {
        float s0 = score[0] * invN, s1 = score[1] * invN;
        float mm = fmaxf(s0, s1);
        float e0 = __expf(s0 - mm), e1 = __expf(s1 - mm);
        float inv = 1.f / (e0 + e1);
        attn[0] = e0 * inv;
        attn[1] = e1 * inv;
    }
}

__global__ __launch_bounds__(256) void k_final(
    const float* __restrict__ o1, const float* __restrict__ o2,
    const float* __restrict__ attn,
    const float* __restrict__ lw, const float* __restrict__ lb,
    float* __restrict__ out, int N)
{
    __shared__ float lwl[FOUT * 2];
    const int tid = threadIdx.x;
    if (tid < FOUT * 2) lwl[tid] = lw[tid];
    __syncthreads();
    const int n = blockIdx.x * 256 + tid;
    if (n >= N) return;
    const float a0 = attn[0], a1 = attn[1];
    float acc0 = lb[0], acc1 = lb[1];
    const float4* p1 = (const float4*)(o1 + (size_t)n * FOUT);
    const float4* p2 = (const float4*)(o2 + (size_t)n * FOUT);
    #pragma unroll
    for (int i = 0; i < FOUT / 4; i++) {
        float4 v1 = p1[i];
        float4 v2 = p2[i];
        float f0 = a0 * v1.x + a1 * v2.x;
        float f1 = a0 * v1.y + a1 * v2.y;
        float f2 = a0 * v1.z + a1 * v2.z;
        float f3 = a0 * v1.w + a1 * v2.w;
        int f = i * 4;
        acc0 += f0 * lwl[f*2]   + f1 * lwl[(f+1)*2]   + f2 * lwl[(f+2)*2]   + f3 * lwl[(f+3)*2];
        acc1 += f0 * lwl[f*2+1] + f1 * lwl[(f+1)*2+1] + f2 * lwl[(f+2)*2+1] + f3 * lwl[(f+3)*2+1];
    }
    *(float2*)(out + (size_t)n * 2) = make_float2(acc0, acc1);
}

extern "C" void kernel_launch(void* const* d_in, const int* in_sizes, int n_in,
                              void* d_out, int out_size, void* d_ws, size_t ws_size,
                              hipStream_t stream)
{
    const float* x_subj = (const float*)d_in[0];
    const float* x_chan = (const float*)d_in[1];
    const int*   e_cs   = (const int*)d_in[2];
    const int*   e_ss   = (const int*)d_in[3];
    const float* W_s    = (const float*)d_in[4];
    const float* b_s    = (const float*)d_in[5];
    const float* W_c    = (const float*)d_in[6];
    const float* b_c    = (const float*)d_in[7];
    const float* att_src_cs = (const float*)d_in[8];
    const float* att_dst_cs = (const float*)d_in[9];
    const float* att_src_ss = (const float*)d_in[10];
    const float* att_dst_ss = (const float*)d_in[11];
    const float* k_w  = (const float*)d_in[12];
    const float* k_b  = (const float*)d_in[13];
    const float* q    = (const float*)d_in[14];
    const float* lw   = (const float*)d_in[15];
    const float* lb   = (const float*)d_in[16];

    const int Ns  = in_sizes[0] / DIN;
    const int Nc  = in_sizes[1] / DIN;
    const int Ecs = in_sizes[2] / 2;
    const int Ess = in_sizes[3] / 2;

    // workspace layout (floats); tail region [s_cs .. score] is the zeroed area
    float* ws = (float*)d_ws;
    size_t off = 0;
    float* hs        = ws + off; off += (size_t)Ns * FOUT;
    float* hc        = ws + off; off += (size_t)Nc * FOUT;
    float* a_src_cs_ = ws + off; off += (size_t)Nc * HH;
    float* a_dst_cs_ = ws + off; off += (size_t)Ns * HH;
    float* a_src_ss_ = ws + off; off += (size_t)Ns * HH;
    float* a_dst_ss_ = ws + off; off += (size_t)Ns * HH;
    float* zstart    = ws + off;
    float* s_cs      = ws + off; off += (size_t)Ns * HH;
    float* s_ss      = ws + off; off += (size_t)Ns * HH;
    float* o1        = ws + off; off += (size_t)Ns * FOUT;
    float* o2        = ws + off; off += (size_t)Ns * FOUT;
    float* score     = ws + off; off += 4;   // [score0, score1, attn0, attn1]
    const size_t zfloats = (size_t)Ns * HH * 2 + (size_t)Ns * FOUT * 2 + 4;
    hipMemsetAsync(zstart, 0, zfloats * sizeof(float), stream);

    // feature transforms + attention logits (subject needs 3 logit sets, channel 1)
    k_lin<<<dim3((Ns + 255) / 256), dim3(256), 0, stream>>>(
        x_subj, W_s, b_s, att_dst_cs, att_src_ss, att_dst_ss,
        hs, a_dst_cs_, a_src_ss_, a_dst_ss_, Ns, 3);
    k_lin<<<dim3((Nc + 255) / 256), dim3(256), 0, stream>>>(
        x_chan, W_c, b_c, att_src_cs, att_src_cs, att_src_cs,
        hc, a_src_cs_, a_src_cs_, a_src_cs_, Nc, 1);

    // edge aggregation (num + den in one pass, wave per edge)
    k_msg<<<dim3((int)(((size_t)Ecs * 64 + 255) / 256)), dim3(256), 0, stream>>>(
        e_cs, Ecs, hc, a_src_cs_, a_dst_cs_, o1, s_cs);
    k_msg<<<dim3((int)(((size_t)Ess * 64 + 255) / 256)), dim3(256), 0, stream>>>(
        e_ss, Ess, hs, a_src_ss_, a_dst_ss_, o2, s_ss);

    // normalize+relu (in place) + semantic score reduction
    k_sem<<<dim3((Ns + 255) / 256, 2), dim3(256), 0, stream>>>(
        o1, o2, s_cs, s_ss, k_w, k_b, q, score, Ns);
    k_attn<<<dim3(1), dim3(64), 0, stream>>>(score, score + 2, 1.f / (float)Ns);
    k_final<<<dim3((Ns + 255) / 256), dim3(256), 0, stream>>>(
        o1, o2, score + 2, lw, lb, (float*)d_out, Ns);
}

// Round 2
// 413.100 us; speedup vs baseline: 3.9091x; 3.9091x over previous
//
#include <hip/hip_runtime.h>

#define HH 8
#define FOUT 128
#define DIN 64
#define NSLOPE 0.2f

typedef __attribute__((ext_vector_type(8))) short bf16x8;
typedef __attribute__((ext_vector_type(4))) float f32x4;

__device__ __forceinline__ float fast_rcp(float x) { return __builtin_amdgcn_rcpf(x); }

__device__ __forceinline__ float fast_tanh(float x) {
    float ax = fabsf(x);
    float e = __expf(-2.f * ax);
    float r = (1.f - e) * fast_rcp(1.f + e);
    return x >= 0.f ? r : -r;
}

__device__ __forceinline__ unsigned short f2bf(float f) {
    unsigned u = __builtin_bit_cast(unsigned, f);
    unsigned r = (u + 0x7fffu + ((u >> 16) & 1u)) >> 16;
    return (unsigned short)r;
}

// ---------------- feature transform (unchanged this round) ----------------
__global__ __launch_bounds__(256) void k_lin(
    const float* __restrict__ x, const float* __restrict__ W, const float* __restrict__ b,
    const float* __restrict__ att0, const float* __restrict__ att1, const float* __restrict__ att2,
    float* __restrict__ hout,
    float* __restrict__ a0, float* __restrict__ a1, float* __restrict__ a2,
    int N, int natt)
{
    __shared__ float Wl[DIN * FOUT];
    __shared__ float bl[FOUT];
    __shared__ float attl[3][FOUT];
    const int tid = threadIdx.x;
    for (int i = tid; i < DIN * FOUT / 4; i += 256)
        ((float4*)Wl)[i] = ((const float4*)W)[i];
    if (tid < FOUT) {
        bl[tid] = b[tid];
        attl[0][tid] = att0[tid];
        attl[1][tid] = natt > 1 ? att1[tid] : 0.f;
        attl[2][tid] = natt > 2 ? att2[tid] : 0.f;
    }
    __syncthreads();
    const int n = blockIdx.x * 256 + tid;
    if (n >= N) return;

    float xr[DIN];
    const float4* xp = (const float4*)(x + (size_t)n * DIN);
    #pragma unroll
    for (int i = 0; i < DIN / 4; i++) {
        float4 v = xp[i];
        xr[4*i] = v.x; xr[4*i+1] = v.y; xr[4*i+2] = v.z; xr[4*i+3] = v.w;
    }
    float4* hp = (float4*)(hout + (size_t)n * FOUT);
    for (int h = 0; h < HH; h++) {
        float aa0 = 0.f, aa1 = 0.f, aa2 = 0.f;
        #pragma unroll
        for (int g = 0; g < 4; g++) {
            const int fo = h * 16 + g * 4;
            float4 acc = *(const float4*)&bl[fo];
            #pragma unroll
            for (int fi = 0; fi < DIN; fi++) {
                float4 wv = *(const float4*)&Wl[fi * FOUT + fo];
                float xv = xr[fi];
                acc.x = fmaf(xv, wv.x, acc.x);
                acc.y = fmaf(xv, wv.y, acc.y);
                acc.z = fmaf(xv, wv.z, acc.z);
                acc.w = fmaf(xv, wv.w, acc.w);
            }
            hp[h * 4 + g] = acc;
            float4 t0 = *(const float4*)&attl[0][fo];
            aa0 += acc.x*t0.x + acc.y*t0.y + acc.z*t0.z + acc.w*t0.w;
            if (natt > 1) {
                float4 t1 = *(const float4*)&attl[1][fo];
                aa1 += acc.x*t1.x + acc.y*t1.y + acc.z*t1.z + acc.w*t1.w;
                float4 t2 = *(const float4*)&attl[2][fo];
                aa2 += acc.x*t2.x + acc.y*t2.y + acc.z*t2.z + acc.w*t2.w;
            }
        }
        a0[(size_t)n * HH + h] = aa0;
        if (natt > 1) {
            a1[(size_t)n * HH + h] = aa1;
            a2[(size_t)n * HH + h] = aa2;
        }
    }
}

// ---------------- CSR build ----------------
__global__ __launch_bounds__(256) void k_deg(const int* __restrict__ edges, int E, int* __restrict__ deg) {
    int e = blockIdx.x * 256 + threadIdx.x;
    if (e < E) atomicAdd(&deg[edges[E + e]], 1);
}

__global__ __launch_bounds__(256) void k_scan_block(
    const int* __restrict__ in, int* __restrict__ out, int* __restrict__ bsum, int n)
{
    __shared__ int s[256];
    const int tid = threadIdx.x;
    const int i = blockIdx.x * 256 + tid;
    int v = i < n ? in[i] : 0;
    s[tid] = v; __syncthreads();
    for (int off = 1; off < 256; off <<= 1) {
        int t = tid >= off ? s[tid - off] : 0;
        __syncthreads();
        s[tid] += t;
        __syncthreads();
    }
    if (i < n) out[i] = s[tid] - v;          // exclusive
    if (tid == 255) bsum[blockIdx.x] = s[255];
}

__global__ __launch_bounds__(512) void k_scan_partial(int* __restrict__ bsum, int nb) {
    __shared__ int s[512];
    const int tid = threadIdx.x;
    int v = tid < nb ? bsum[tid] : 0;
    s[tid] = v; __syncthreads();
    for (int off = 1; off < 512; off <<= 1) {
        int t = tid >= off ? s[tid - off] : 0;
        __syncthreads();
        s[tid] += t;
        __syncthreads();
    }
    if (tid < nb) bsum[tid] = s[tid] - v;    // exclusive
}

__global__ __launch_bounds__(256) void k_scan_add(int* __restrict__ out, const int* __restrict__ bsum, int n) {
    int i = blockIdx.x * 256 + threadIdx.x;
    if (i < n) out[i] += bsum[blockIdx.x];
}

__global__ __launch_bounds__(256) void k_scatter(
    const int* __restrict__ edges, int E,
    const int* __restrict__ rowptr, int* __restrict__ cnt, int* __restrict__ srclist)
{
    int e = blockIdx.x * 256 + threadIdx.x;
    if (e >= E) return;
    int src = edges[e], dst = edges[E + e];
    int pos = rowptr[dst] + atomicAdd(&cnt[dst], 1);
    srclist[pos] = src;
}

// ---------------- aggregation: wave per dst, registers only, fused norm+relu ----------------
__global__ __launch_bounds__(256) void k_agg(
    const int* __restrict__ srclist, const int* __restrict__ rowptr, const int* __restrict__ deg,
    const float* __restrict__ xsrc, const float* __restrict__ asrc, const float* __restrict__ adst,
    float* __restrict__ oout, int N)
{
    const int t = blockIdx.x * 256 + threadIdx.x;
    const int dst = t >> 6;
    if (dst >= N) return;
    const int lane = t & 63;
    const int h = lane >> 3;
    const int d = deg[dst];
    const int base = rowptr[dst];
    const float ad = adst[(size_t)dst * HH + h];
    float2 acc = make_float2(0.f, 0.f);
    float wsum = 0.f;
    int src_next = d > 0 ? srclist[base] : 0;
    for (int k = 0; k < d; k++) {
        int src = src_next;
        if (k + 1 < d) src_next = srclist[base + k + 1];
        float a = asrc[(size_t)src * HH + h] + ad;
        a = a > 0.f ? a : NSLOPE * a;
        float wv = __expf(a);
        float2 xv = *(const float2*)&xsrc[(size_t)src * FOUT + lane * 2];
        acc.x = fmaf(wv, xv.x, acc.x);
        acc.y = fmaf(wv, xv.y, acc.y);
        wsum += wv;
    }
    float inv = fast_rcp(wsum + 1e-16f);
    float2 o = make_float2(fmaxf(acc.x * inv, 0.f), fmaxf(acc.y * inv, 0.f));
    *(float2*)&oout[(size_t)dst * FOUT + lane * 2] = o;
}

// ---------------- semantic score: bf16 MFMA GEMM + tanh·q reduce ----------------
// score[m] = sum_n sum_fo q[fo] * tanh((o_m[n,:] @ kw)[fo] + kb[fo])
__global__ __launch_bounds__(256) void k_sem(
    const float* __restrict__ o1, const float* __restrict__ o2,
    const float* __restrict__ kw, const float* __restrict__ kb,
    const float* __restrict__ q, float* __restrict__ score, int N)
{
    __shared__ unsigned short kwl[FOUT * FOUT];  // kw^T in bf16, chunk-XOR swizzled (32 KB)
    __shared__ float red[256];
    const int tid = threadIdx.x;
    const int m = blockIdx.y;
    const float* o = m ? o2 : o1;

    // stage kw^T bf16: element (fi,fo) -> row fo, 8-elem chunk (fi>>3)^(fo&15), slot fi&7
    for (int idx = tid; idx < FOUT * FOUT; idx += 256) {
        int fi = idx >> 7, fo = idx & 127;
        int c = (fi >> 3) ^ (fo & 15);
        kwl[fo * 128 + c * 8 + (fi & 7)] = f2bf(kw[idx]);
    }
    __syncthreads();

    const int lane = tid & 63;
    const int w = tid >> 6;
    const int n0 = blockIdx.x * 256 + w * 64;
    const int r16 = lane & 15;
    const int g = lane >> 4;

    float qv[8], kbv[8];
    #pragma unroll
    for (int j = 0; j < 8; j++) { qv[j] = q[j * 16 + r16]; kbv[j] = kb[j * 16 + r16]; }

    // A fragments: lane holds o[node = n0+i*16+(lane&15)][k = kk*32 + (lane>>4)*8 + b]
    bf16x8 afrag[4][4];
    #pragma unroll
    for (int i = 0; i < 4; i++) {
        int node = n0 + i * 16 + r16;
        if (node > N - 1) node = N - 1;
        const float* rowp = o + (size_t)node * FOUT + g * 8;
        #pragma unroll
        for (int kk = 0; kk < 4; kk++) {
            float4 v0 = *(const float4*)(rowp + kk * 32);
            float4 v1 = *(const float4*)(rowp + kk * 32 + 4);
            bf16x8 f;
            f[0] = (short)f2bf(v0.x); f[1] = (short)f2bf(v0.y);
            f[2] = (short)f2bf(v0.z); f[3] = (short)f2bf(v0.w);
            f[4] = (short)f2bf(v1.x); f[5] = (short)f2bf(v1.y);
            f[6] = (short)f2bf(v1.z); f[7] = (short)f2bf(v1.w);
            afrag[i][kk] = f;
        }
    }

    float part = 0.f;
    #pragma unroll
    for (int j = 0; j < 8; j++) {
        const int fo = j * 16 + r16;
        f32x4 acc0 = {0.f,0.f,0.f,0.f}, acc1 = {0.f,0.f,0.f,0.f};
        f32x4 acc2 = {0.f,0.f,0.f,0.f}, acc3 = {0.f,0.f,0.f,0.f};
        #pragma unroll
        for (int kk = 0; kk < 4; kk++) {
            int c = (kk * 4 + g) ^ (fo & 15);
            bf16x8 bfr = *(bf16x8*)&kwl[fo * 128 + c * 8];
            acc0 = __builtin_amdgcn_mfma_f32_16x16x32_bf16(afrag[0][kk], bfr, acc0, 0, 0, 0);
            acc1 = __builtin_amdgcn_mfma_f32_16x16x32_bf16(afrag[1][kk], bfr, acc1, 0, 0, 0);
            acc2 = __builtin_amdgcn_mfma_f32_16x16x32_bf16(afrag[2][kk], bfr, acc2, 0, 0, 0);
            acc3 = __builtin_amdgcn_mfma_f32_16x16x32_bf16(afrag[3][kk], bfr, acc3, 0, 0, 0);
        }
        // D: lane holds D[node = n0+i*16+4*(lane>>4)+r][fo = j*16+(lane&15)]
        #pragma unroll
        for (int i = 0; i < 4; i++) {
            f32x4 a = i == 0 ? acc0 : (i == 1 ? acc1 : (i == 2 ? acc2 : acc3));
            #pragma unroll
            for (int r = 0; r < 4; r++) {
                int node = n0 + i * 16 + g * 4 + r;
                if (node < N) part += fast_tanh(a[r] + kbv[j]) * qv[j];
            }
        }
    }
    red[tid] = part;
    __syncthreads();
    for (int s2 = 128; s2 > 0; s2 >>= 1) {
        if (tid < s2) red[tid] += red[tid + s2];
        __syncthreads();
    }
    if (tid == 0) atomicAdd(score + m, red[0]);
}

__global__ void k_attn(const float* __restrict__ score, float* __restrict__ attn, float invN) {
    if (threadIdx.x == 0) {
        float s0 = score[0] * invN, s1 = score[1] * invN;
        float mm = fmaxf(s0, s1);
        float e0 = __expf(s0 - mm), e1 = __expf(s1 - mm);
        float inv = 1.f / (e0 + e1);
        attn[0] = e0 * inv;
        attn[1] = e1 * inv;
    }
}

__global__ __launch_bounds__(256) void k_final(
    const float* __restrict__ o1, const float* __restrict__ o2,
    const float* __restrict__ attn,
    const float* __restrict__ lw, const float* __restrict__ lb,
    float* __restrict__ out, int N)
{
    __shared__ float lwl[FOUT * 2];
    const int tid = threadIdx.x;
    if (tid < FOUT * 2) lwl[tid] = lw[tid];
    __syncthreads();
    const int n = blockIdx.x * 256 + tid;
    if (n >= N) return;
    const float a0 = attn[0], a1 = attn[1];
    float acc0 = lb[0], acc1 = lb[1];
    const float4* p1 = (const float4*)(o1 + (size_t)n * FOUT);
    const float4* p2 = (const float4*)(o2 + (size_t)n * FOUT);
    #pragma unroll
    for (int i = 0; i < FOUT / 4; i++) {
        float4 v1 = p1[i];
        float4 v2 = p2[i];
        float f0 = a0 * v1.x + a1 * v2.x;
        float f1 = a0 * v1.y + a1 * v2.y;
        float f2 = a0 * v1.z + a1 * v2.z;
        float f3 = a0 * v1.w + a1 * v2.w;
        int f = i * 4;
        acc0 += f0 * lwl[f*2]   + f1 * lwl[(f+1)*2]   + f2 * lwl[(f+2)*2]   + f3 * lwl[(f+3)*2];
        acc1 += f0 * lwl[f*2+1] + f1 * lwl[(f+1)*2+1] + f2 * lwl[(f+2)*2+1] + f3 * lwl[(f+3)*2+1];
    }
    *(float2*)(out + (size_t)n * 2) = make_float2(acc0, acc1);
}

extern "C" void kernel_launch(void* const* d_in, const int* in_sizes, int n_in,
                              void* d_out, int out_size, void* d_ws, size_t ws_size,
                              hipStream_t stream)
{
    const float* x_subj = (const float*)d_in[0];
    const float* x_chan = (const float*)d_in[1];
    const int*   e_cs   = (const int*)d_in[2];
    const int*   e_ss   = (const int*)d_in[3];
    const float* W_s    = (const float*)d_in[4];
    const float* b_s    = (const float*)d_in[5];
    const float* W_c    = (const float*)d_in[6];
    const float* b_c    = (const float*)d_in[7];
    const float* att_src_cs = (const float*)d_in[8];
    const float* att_dst_cs = (const float*)d_in[9];
    const float* att_src_ss = (const float*)d_in[10];
    const float* att_dst_ss = (const float*)d_in[11];
    const float* k_w  = (const float*)d_in[12];
    const float* k_b  = (const float*)d_in[13];
    const float* q    = (const float*)d_in[14];
    const float* lw   = (const float*)d_in[15];
    const float* lb   = (const float*)d_in[16];

    const int Ns  = in_sizes[0] / DIN;
    const int Nc  = in_sizes[1] / DIN;
    const int Ecs = in_sizes[2] / 2;
    const int Ess = in_sizes[3] / 2;

    // ---- workspace layout ----
    char* p = (char*)d_ws;
    float* hs        = (float*)p; p += (size_t)Ns * FOUT * 4;
    float* hc        = (float*)p; p += (size_t)Nc * FOUT * 4;
    float* a_src_cs_ = (float*)p; p += (size_t)Nc * HH * 4;
    float* a_dst_cs_ = (float*)p; p += (size_t)Ns * HH * 4;
    float* a_src_ss_ = (float*)p; p += (size_t)Ns * HH * 4;
    float* a_dst_ss_ = (float*)p; p += (size_t)Ns * HH * 4;
    float* o1        = (float*)p; p += (size_t)Ns * FOUT * 4;
    float* o2        = (float*)p; p += (size_t)Ns * FOUT * 4;
    int* srclist_cs  = (int*)p;   p += (size_t)Ecs * 4;
    int* srclist_ss  = (int*)p;   p += (size_t)Ess * 4;
    int* rowptr_cs   = (int*)p;   p += (size_t)Ns * 4;
    int* rowptr_ss   = (int*)p;   p += (size_t)Ns * 4;
    int* bsum        = (int*)p;   p += 2048;
    // zeroed region:
    char* zstart = p;
    int* deg_cs = (int*)p; p += (size_t)Ns * 4;
    int* deg_ss = (int*)p; p += (size_t)Ns * 4;
    int* cnt_cs = (int*)p; p += (size_t)Ns * 4;
    int* cnt_ss = (int*)p; p += (size_t)Ns * 4;
    float* score = (float*)p; p += 16;   // [s0, s1, attn0, attn1]
    hipMemsetAsync(zstart, 0, (size_t)Ns * 4 * 4 + 16, stream);

    const int nbN = (Ns + 255) / 256;

    // feature transforms + attention logits
    k_lin<<<dim3(nbN), dim3(256), 0, stream>>>(
        x_subj, W_s, b_s, att_dst_cs, att_src_ss, att_dst_ss,
        hs, a_dst_cs_, a_src_ss_, a_dst_ss_, Ns, 3);
    k_lin<<<dim3((Nc + 255) / 256), dim3(256), 0, stream>>>(
        x_chan, W_c, b_c, att_src_cs, att_src_cs, att_src_cs,
        hc, a_src_cs_, a_src_cs_, a_src_cs_, Nc, 1);

    // ---- CSR build: cs ----
    k_deg<<<dim3((Ecs + 255) / 256), dim3(256), 0, stream>>>(e_cs, Ecs, deg_cs);
    k_scan_block<<<dim3(nbN), dim3(256), 0, stream>>>(deg_cs, rowptr_cs, bsum, Ns);
    k_scan_partial<<<dim3(1), dim3(512), 0, stream>>>(bsum, nbN);
    k_scan_add<<<dim3(nbN), dim3(256), 0, stream>>>(rowptr_cs, bsum, Ns);
    k_scatter<<<dim3((Ecs + 255) / 256), dim3(256), 0, stream>>>(e_cs, Ecs, rowptr_cs, cnt_cs, srclist_cs);
    // ---- CSR build: ss ----
    k_deg<<<dim3((Ess + 255) / 256), dim3(256), 0, stream>>>(e_ss, Ess, deg_ss);
    k_scan_block<<<dim3(nbN), dim3(256), 0, stream>>>(deg_ss, rowptr_ss, bsum, Ns);
    k_scan_partial<<<dim3(1), dim3(512), 0, stream>>>(bsum, nbN);
    k_scan_add<<<dim3(nbN), dim3(256), 0, stream>>>(rowptr_ss, bsum, Ns);
    k_scatter<<<dim3((Ess + 255) / 256), dim3(256), 0, stream>>>(e_ss, Ess, rowptr_ss, cnt_ss, srclist_ss);

    // ---- aggregation (fused softmax-normalize + relu) ----
    k_agg<<<dim3((Ns * 64 + 255) / 256), dim3(256), 0, stream>>>(
        srclist_cs, rowptr_cs, deg_cs, hc, a_src_cs_, a_dst_cs_, o1, Ns);
    k_agg<<<dim3((Ns * 64 + 255) / 256), dim3(256), 0, stream>>>(
        srclist_ss, rowptr_ss, deg_ss, hs, a_src_ss_, a_dst_ss_, o2, Ns);

    // ---- semantic attention + fuse + output ----
    k_sem<<<dim3(nbN, 2), dim3(256), 0, stream>>>(o1, o2, k_w, k_b, q, score, Ns);
    k_attn<<<dim3(1), dim3(64), 0, stream>>>(score, score + 2, 1.f / (float)Ns);
    k_final<<<dim3(nbN), dim3(256), 0, stream>>>(o1, o2, score + 2, lw, lb, (float*)d_out, Ns);
}